// Round 8
// baseline (273.993 us; speedup 1.0000x reference)
//
#include <hip/hip_runtime.h>
#include <math.h>

#define NB 4096
#define PAD 2048
#define TPB 256        // 4 waves per block
#define RPW 4          // rows per wave

typedef float f32x4 __attribute__((ext_vector_type(4)));

__device__ __forceinline__ int mirror_idx(int i) {
    // valid for i in [-PAD, NB+PAD-2]; single reflection
    i = ::abs(i);
    return (i < NB) ? i : (2 * (NB - 1) - i);
}

// Precompute p = sigmoid(logits), lsp = log_sigmoid(logits), lsn = log_sigmoid(-logits)
__global__ void fbmp_precompute(const float* __restrict__ logits, float* __restrict__ ws) {
    int j = blockIdx.x * blockDim.x + threadIdx.x;
    if (j >= NB) return;
    float x = logits[j];
    double xd = (double)x;
    float e = (float)exp(-xd);
    float p = 1.0f / (1.0f + e);
    float lsp = (float)(-log1p(exp(-xd)));  // log_sigmoid(x)
    float lsn = (float)(-log1p(exp(xd)));   // log_sigmoid(-x)
    ws[j] = p;
    ws[NB + j] = lsp;
    ws[2 * NB + j] = lsn;
}

// One row of work: prefetch next row's u (vmcnt-only), compute current row from
// registers + LDS tables (lgkmcnt-only), ballot-pack bits to wave-private LDS,
// logp (bit-exact structure from verified rounds), then 16 NT dwordx4 stores.
// Stores depend only on LDS -> they issue while next row's loads are in flight.
#define PIPE_ROW(R, C, N, S)                                                   \
  if ((R) < myrows) {                                                          \
    const int row = base + (R);                                                \
    if ((R) + 1 < myrows) {                                                    \
      const float4* __restrict__ nr4 =                                         \
          (const float4*)(u + (size_t)(row + 1) * NB);                         \
      _Pragma("unroll")                                                        \
      for (int c = 0; c < 16; ++c) N[c] = nr4[lane + 64 * c];                  \
    }                                                                          \
    float accw0 = 0.f, accw1 = 0.f, accw2 = 0.f, accw3 = 0.f;                  \
    unsigned long long myword = 0ull;                                          \
    _Pragma("unroll")                                                          \
    for (int c = 0; c < 16; ++c) {                                             \
      const int i = lane + 64 * c;                                             \
      float4 pv = p4[i];                                                       \
      float4 ap = lsp4[i];                                                     \
      float4 an = lsn4[i];                                                     \
      bool c0 = C[c].x < pv.x;                                                 \
      bool c1 = C[c].y < pv.y;                                                 \
      bool c2 = C[c].z < pv.z;                                                 \
      bool c3 = C[c].w < pv.w;                                                 \
      float term = (c0 ? ap.x : an.x) + (c1 ? ap.y : an.y)                     \
                 + (c2 ? ap.z : an.z) + (c3 ? ap.w : an.w);                    \
      if ((c & 3) == 0) accw0 += term;                                         \
      else if ((c & 3) == 1) accw1 += term;                                    \
      else if ((c & 3) == 2) accw2 += term;                                    \
      else accw3 += term;                                                      \
      unsigned long long b0 = __ballot(c0);                                    \
      unsigned long long b1 = __ballot(c1);                                    \
      unsigned long long b2 = __ballot(c2);                                    \
      unsigned long long b3 = __ballot(c3);                                    \
      if ((lane >> 2) == c) {                                                  \
        unsigned long long m0 = (lane & 1) ? b1 : b0;                          \
        unsigned long long m1 = (lane & 1) ? b3 : b2;                          \
        myword = (lane & 2) ? m1 : m0;                                         \
      }                                                                        \
    }                                                                          \
    words[wid][lane] = myword;                                                 \
    _Pragma("unroll")                                                          \
    for (int off = 32; off > 0; off >>= 1) {                                   \
      accw0 += __shfl_down(accw0, off, 64);                                    \
      accw1 += __shfl_down(accw1, off, 64);                                    \
      accw2 += __shfl_down(accw2, off, 64);                                    \
      accw3 += __shfl_down(accw3, off, 64);                                    \
    }                                                                          \
    if (lane == 0) {                                                           \
      float tt = 0.0f;                                                         \
      tt += accw0;                                                             \
      tt += accw1;                                                             \
      tt += accw2;                                                             \
      tt += accw3;                                                             \
      logp[row] = tt;                                                          \
    }                                                                          \
    const unsigned int* __restrict__ w32 =                                     \
        (const unsigned int*)&words[wid][0];                                   \
    float* __restrict__ mrow = masks + (size_t)row * NB;                       \
    _Pragma("unroll")                                                          \
    for (int c = 0; c < 16; ++c) {                                             \
      const int i = lane + 64 * c;                                             \
      const int k = 4 * i + (S);                                               \
      f32x4 o;                                                                 \
      {                                                                        \
        const int j = mirror_idx(k + 0);                                       \
        const int w64 = ((j >> 8) << 2) | (j & 3);                             \
        const int bit = (j >> 2) & 63;                                         \
        o.x = ((w32[(w64 << 1) | (bit >> 5)] >> (bit & 31)) & 1u) ? 1.0f : 0.0f; \
      }                                                                        \
      {                                                                        \
        const int j = mirror_idx(k + 1);                                       \
        const int w64 = ((j >> 8) << 2) | (j & 3);                             \
        const int bit = (j >> 2) & 63;                                         \
        o.y = ((w32[(w64 << 1) | (bit >> 5)] >> (bit & 31)) & 1u) ? 1.0f : 0.0f; \
      }                                                                        \
      {                                                                        \
        const int j = mirror_idx(k + 2);                                       \
        const int w64 = ((j >> 8) << 2) | (j & 3);                             \
        const int bit = (j >> 2) & 63;                                         \
        o.z = ((w32[(w64 << 1) | (bit >> 5)] >> (bit & 31)) & 1u) ? 1.0f : 0.0f; \
      }                                                                        \
      {                                                                        \
        const int j = mirror_idx(k + 3);                                       \
        const int w64 = ((j >> 8) << 2) | (j & 3);                             \
        const int bit = (j >> 2) & 63;                                         \
        o.w = ((w32[(w64 << 1) | (bit >> 5)] >> (bit & 31)) & 1u) ? 1.0f : 0.0f; \
      }                                                                        \
      __builtin_nontemporal_store(o, (f32x4*)mrow + i);                        \
    }                                                                          \
  }

__global__ __launch_bounds__(TPB, 2) void fbmp_pipe(
    const float* __restrict__ u, const int* __restrict__ shift,
    const float* __restrict__ ws,
    float* __restrict__ masks, float* __restrict__ logp, int B)
{
    __shared__ float tbl[3 * NB];                      // 48 KB: p, lsp, lsn
    __shared__ unsigned long long words[TPB / 64][64]; // 2 KB wave-private bits

    const int t = threadIdx.x;
    // stage tables once per block (12 float4 per thread)
    {
        const float4* __restrict__ src = (const float4*)ws;
        float4* __restrict__ dst = (float4*)tbl;
        #pragma unroll
        for (int c = 0; c < (3 * NB / 4) / TPB; ++c)
            dst[t + c * TPB] = src[t + c * TPB];
    }
    __syncthreads();   // only barrier

    const int lane = t & 63;
    const int wid  = t >> 6;
    const int gw   = blockIdx.x * (TPB / 64) + wid;
    const int base = gw * RPW;
    if (base >= B) return;                             // wave-uniform
    const int myrows = (B - base < RPW) ? (B - base) : RPW;

    const float4* __restrict__ p4   = (const float4*)tbl;
    const float4* __restrict__ lsp4 = (const float4*)(tbl + NB);
    const float4* __restrict__ lsn4 = (const float4*)(tbl + 2 * NB);

    // all shifts up-front: never awaited mid-pipeline (vmcnt stays clean)
    const int s0 = shift[base] - PAD;
    const int s1 = (myrows > 1) ? shift[base + 1] - PAD : 0;
    const int s2 = (myrows > 2) ? shift[base + 2] - PAD : 0;
    const int s3 = (myrows > 3) ? shift[base + 3] - PAD : 0;

    float4 bufA[16], bufB[16];
    {
        const float4* __restrict__ r4 = (const float4*)(u + (size_t)base * NB);
        #pragma unroll
        for (int c = 0; c < 16; ++c) bufA[c] = r4[lane + 64 * c];
    }

    PIPE_ROW(0, bufA, bufB, s0)
    PIPE_ROW(1, bufB, bufA, s1)
    PIPE_ROW(2, bufA, bufB, s2)
    PIPE_ROW(3, bufB, bufA, s3)
}

extern "C" void kernel_launch(void* const* d_in, const int* in_sizes, int n_in,
                              void* d_out, int out_size, void* d_ws, size_t ws_size,
                              hipStream_t stream) {
    const float* logits = (const float*)d_in[0];
    const float* u      = (const float*)d_in[1];
    const int*   shift  = (const int*)d_in[2];
    const int B = in_sizes[2];

    float* ws    = (float*)d_ws;                    // 3*NB floats (tables)
    float* masks = (float*)d_out;                   // B*NB
    float* logp  = (float*)d_out + (size_t)B * NB;  // B

    fbmp_precompute<<<(NB + 255) / 256, 256, 0, stream>>>(logits, ws);

    const int waves = (B + RPW - 1) / RPW;
    const int grid  = (waves + (TPB / 64) - 1) / (TPB / 64);
    fbmp_pipe<<<grid, TPB, 0, stream>>>(u, shift, ws, masks, logp, B);
}

// Round 9
// 261.211 us; speedup vs baseline: 1.0489x; 1.0489x over previous
//
#include <hip/hip_runtime.h>
#include <math.h>

#define NB 4096
#define PAD 2048
#define TPB 512          // 8 waves: 4 producers + 4 consumers
#define PW 4             // producer waves == rows per set
#define KSETS 4          // sets per block -> PW*KSETS = 16 rows per block

typedef float f32x4 __attribute__((ext_vector_type(4)));

__device__ __forceinline__ int mirror_idx(int i) {
    // valid for i in [-PAD, NB+PAD-2]; single reflection
    i = ::abs(i);
    return (i < NB) ? i : (2 * (NB - 1) - i);
}

// Precompute p = sigmoid(logits), lsp = log_sigmoid(logits), lsn = log_sigmoid(-logits)
__global__ void fbmp_precompute(const float* __restrict__ logits, float* __restrict__ ws) {
    int j = blockIdx.x * blockDim.x + threadIdx.x;
    if (j >= NB) return;
    float x = logits[j];
    double xd = (double)x;
    float e = (float)exp(-xd);
    float p = 1.0f / (1.0f + e);
    float lsp = (float)(-log1p(exp(-xd)));  // log_sigmoid(x)
    float lsn = (float)(-log1p(exp(xd)));   // log_sigmoid(-x)
    ws[j] = p;
    ws[NB + j] = lsp;
    ws[2 * NB + j] = lsn;
}

// Producer/consumer wave-specialized kernel.
// Producer wave p (wv<PW), interval s: row = b0 + s*PW + p.
//   16 coalesced dwordx4 u-loads -> compare vs LDS tables -> ballot-pack row
//   bits (verified round-6 mapping) into bits[s&1][p][lane] -> logp (bit-exact
//   accumulator structure). vmcnt queue holds ONLY u-loads.
// Consumer wave c (wv>=PW), interval s: row = b0 + (s-1)*PW + c.
//   LDS broadcast bit-expand (lane-uniform word index, conflict-free) ->
//   16 back-to-back NT dwordx4 stores. vmcnt queue holds ONLY stores.
// One __syncthreads per interval separates bits[s] production from its
// consumption; producers of set s run concurrently with consumers of set s-1
// -> HBM reads and writes simultaneously in flight per CU.
__global__ __launch_bounds__(TPB, 4) void fbmp_pc(
    const float* __restrict__ u, const int* __restrict__ shift,
    const float* __restrict__ ws,
    float* __restrict__ masks, float* __restrict__ logp, int B)
{
    __shared__ float tbl[3 * NB];                      // 48 KB: p, lsp, lsn
    __shared__ unsigned long long bits[2][PW][64];     // 4 KB double-buffered

    const int t = threadIdx.x;

    // stage tables once per block (6 float4 per thread)
    {
        const float4* __restrict__ src = (const float4*)ws;
        float4* __restrict__ dst = (float4*)tbl;
        #pragma unroll
        for (int c = 0; c < (3 * NB / 4) / TPB; ++c)
            dst[t + c * TPB] = src[t + c * TPB];
    }

    const int lane = t & 63;
    const int wv   = t >> 6;                 // 0..7
    const bool producer = (wv < PW);
    const int role = producer ? wv : (wv - PW);
    const int b0 = blockIdx.x * (PW * KSETS);

    // consumers preload all their shifts (tiny; never awaited mid-pipeline)
    int sh[KSETS];
    if (!producer) {
        #pragma unroll
        for (int s = 0; s < KSETS; ++s) {
            const int row = b0 + s * PW + role;
            sh[s] = (row < B) ? (shift[row] - PAD) : 0;
        }
    }
    __syncthreads();                          // tables ready

    const float4* __restrict__ p4   = (const float4*)tbl;
    const float4* __restrict__ lsp4 = (const float4*)(tbl + NB);
    const float4* __restrict__ lsn4 = (const float4*)(tbl + 2 * NB);

    for (int s = 0; s <= KSETS; ++s) {        // block-uniform loop
        if (producer && s < KSETS) {
            const int row = b0 + s * PW + role;
            if (row < B) {                    // wave-uniform
                const float4* __restrict__ u4 = (const float4*)(u + (size_t)row * NB);
                float4 uvv[16];
                #pragma unroll
                for (int c = 0; c < 16; ++c) uvv[c] = u4[lane + 64 * c];

                float accw[4] = {0.0f, 0.0f, 0.0f, 0.0f};
                unsigned long long myword = 0ull;
                #pragma unroll
                for (int c = 0; c < 16; ++c) {
                    const int i = lane + 64 * c;
                    float4 pv = p4[i];
                    float4 ap = lsp4[i];
                    float4 an = lsn4[i];
                    bool c0 = uvv[c].x < pv.x;
                    bool c1 = uvv[c].y < pv.y;
                    bool c2 = uvv[c].z < pv.z;
                    bool c3 = uvv[c].w < pv.w;
                    // identical quad association as the verified kernel
                    accw[c & 3] += (c0 ? ap.x : an.x) + (c1 ? ap.y : an.y)
                                 + (c2 ? ap.z : an.z) + (c3 ? ap.w : an.w);
                    unsigned long long b0w = __ballot(c0);
                    unsigned long long b1w = __ballot(c1);
                    unsigned long long b2w = __ballot(c2);
                    unsigned long long b3w = __ballot(c3);
                    if ((lane >> 2) == c) {   // lane owns u64 word #lane
                        unsigned long long m0 = (lane & 1) ? b1w : b0w;
                        unsigned long long m1 = (lane & 1) ? b3w : b2w;
                        myword = (lane & 2) ? m1 : m0;
                    }
                }
                bits[s & 1][role][lane] = myword;

                // logp: per-original-wave shuffle trees + identical summation order
                #pragma unroll
                for (int w = 0; w < 4; ++w) {
                    #pragma unroll
                    for (int off = 32; off > 0; off >>= 1)
                        accw[w] += __shfl_down(accw[w], off, 64);
                }
                if (lane == 0) {
                    float tt = 0.0f;
                    tt += accw[0];
                    tt += accw[1];
                    tt += accw[2];
                    tt += accw[3];
                    logp[row] = tt;
                }
            }
        }
        if (!producer && s >= 1) {
            const int ss = s - 1;
            const int row = b0 + ss * PW + role;
            if (row < B) {                    // wave-uniform
                const unsigned int* __restrict__ w32 =
                    (const unsigned int*)&bits[ss & 1][role][0];
                float* __restrict__ mrow = masks + (size_t)row * NB;
                const int sshift = sh[ss];
                #pragma unroll
                for (int c = 0; c < 16; ++c) {
                    const int i = lane + 64 * c;
                    const int k = 4 * i + sshift;
                    f32x4 o;
                    {
                        const int j = mirror_idx(k + 0);
                        const int w64 = ((j >> 8) << 2) | (j & 3);
                        const int bit = (j >> 2) & 63;
                        o.x = ((w32[(w64 << 1) | (bit >> 5)] >> (bit & 31)) & 1u) ? 1.0f : 0.0f;
                    }
                    {
                        const int j = mirror_idx(k + 1);
                        const int w64 = ((j >> 8) << 2) | (j & 3);
                        const int bit = (j >> 2) & 63;
                        o.y = ((w32[(w64 << 1) | (bit >> 5)] >> (bit & 31)) & 1u) ? 1.0f : 0.0f;
                    }
                    {
                        const int j = mirror_idx(k + 2);
                        const int w64 = ((j >> 8) << 2) | (j & 3);
                        const int bit = (j >> 2) & 63;
                        o.z = ((w32[(w64 << 1) | (bit >> 5)] >> (bit & 31)) & 1u) ? 1.0f : 0.0f;
                    }
                    {
                        const int j = mirror_idx(k + 3);
                        const int w64 = ((j >> 8) << 2) | (j & 3);
                        const int bit = (j >> 2) & 63;
                        o.w = ((w32[(w64 << 1) | (bit >> 5)] >> (bit & 31)) & 1u) ? 1.0f : 0.0f;
                    }
                    __builtin_nontemporal_store(o, (f32x4*)mrow + i);
                }
            }
        }
        __syncthreads();   // set s published; set s-1 fully consumed
    }
}

extern "C" void kernel_launch(void* const* d_in, const int* in_sizes, int n_in,
                              void* d_out, int out_size, void* d_ws, size_t ws_size,
                              hipStream_t stream) {
    const float* logits = (const float*)d_in[0];
    const float* u      = (const float*)d_in[1];
    const int*   shift  = (const int*)d_in[2];
    const int B = in_sizes[2];

    float* ws    = (float*)d_ws;                    // 3*NB floats (tables)
    float* masks = (float*)d_out;                   // B*NB
    float* logp  = (float*)d_out + (size_t)B * NB;  // B

    fbmp_precompute<<<(NB + 255) / 256, 256, 0, stream>>>(logits, ws);

    const int rows_per_block = PW * KSETS;          // 16
    const int grid = (B + rows_per_block - 1) / rows_per_block;
    fbmp_pc<<<grid, TPB, 0, stream>>>(u, shift, ws, masks, logp, B);
}